// Round 3
// baseline (279.169 us; speedup 1.0000x reference)
//
#include <hip/hip_runtime.h>

#define NF 40
#define NE 128
#define NA 128
#define NP 780        // NF*(NF-1)/2
#define NPT 784       // padded to 49*16
#define NMT 49        // m-tiles of 16 pairs
#define XS_LD 132     // x LDS row stride (floats): 16B aligned, spreads banks

typedef short short8 __attribute__((ext_vector_type(8)));
typedef float floatx4 __attribute__((ext_vector_type(4)));

__device__ __forceinline__ unsigned cvt_pk_bf16(float lo, float hi) {
    // D[15:0] = bf16(S0), D[31:16] = bf16(S1), RNE
    unsigned r;
    asm("v_cvt_pk_bf16_f32 %0, %1, %2" : "=v"(r) : "v"(lo), "v"(hi));
    return r;
}

// sum across each 16-lane row via DPP row_ror (VALU pipe, no DS traffic)
__device__ __forceinline__ float rowsum16(float x) {
    x += __int_as_float(__builtin_amdgcn_update_dpp(0, __float_as_int(x), 0x121, 0xf, 0xf, true)); // ror:1
    x += __int_as_float(__builtin_amdgcn_update_dpp(0, __float_as_int(x), 0x122, 0xf, 0xf, true)); // ror:2
    x += __int_as_float(__builtin_amdgcn_update_dpp(0, __float_as_int(x), 0x124, 0xf, 0xf, true)); // ror:4
    x += __int_as_float(__builtin_amdgcn_update_dpp(0, __float_as_int(x), 0x128, 0xf, 0xf, true)); // ror:8
    return x;
}

// ---- prep: W fp32 -> bf16 into workspace; pair-index table into workspace ----
__global__ __launch_bounds__(256)
void afm_prep_kernel(const float* __restrict__ wg,
                     unsigned short* __restrict__ wbf,
                     int* __restrict__ ijg)
{
    const int t = blockIdx.x * 256 + threadIdx.x;   // 4096 threads
    if (t < NA * NE / 4) {
        float4 v = *(const float4*)(wg + t * 4);
        uint2 pk;
        pk.x = cvt_pk_bf16(v.x, v.y);
        pk.y = cvt_pk_bf16(v.z, v.w);
        *(uint2*)(wbf + t * 4) = pk;
    }
    if (t < NPT) {
        int v = 0;
        if (t < NP) {
            int i = 0, rem = t;
            while (rem >= (NF - 1 - i)) { rem -= (NF - 1 - i); ++i; }
            v = (i << 8) | (i + 1 + rem);
        }
        ijg[t] = v;
    }
}

__global__ __launch_bounds__(256, 4)
void afm_fused_kernel(const float* __restrict__ xg,          // [B, F, E]
                      const unsigned short* __restrict__ wbf,// [A, E] bf16 (prepped)
                      const int* __restrict__ ijg,           // [NPT] packed (i<<8)|j
                      const float* __restrict__ wbg,         // [A]
                      const float* __restrict__ hg,          // [1, A]
                      const float* __restrict__ pwg,         // [1, E]
                      const float* __restrict__ pbg,         // [1]
                      float* __restrict__ out)               // [B]
{
    __shared__ float xs[NF][XS_LD];          // 21120 B fp32 x
    __shared__ float sc[NPT];                // 3136 B scores -> exp (zero-padded to NPT)
    __shared__ int   ij[NPT];                // 3136 B packed (i<<8)|j (0 for p>=NP)
    __shared__ float afmp[4][NE];            // 2048 B afm partials (per wave)
    __shared__ float red_max[4], red_sum[4], red_out[4];

    const int tid  = threadIdx.x;
    const int b    = blockIdx.x;
    const int lane = tid & 63;
    const int wid  = tid >> 6;
    const int col  = lane & 15;
    const int quad = (lane >> 4) & 3;

    // ---- stage x[b] (fp32) ----
    const float* xb = xg + (size_t)b * (NF * NE);
    for (int t = tid; t < NF * (NE / 4); t += 256) {
        int row = t >> 5, c = (t & 31) * 4;
        float4 v = *(const float4*)(xb + row * NE + c);
        *(float4*)&xs[row][c] = v;
    }
    // ---- pair index table: copy from prepped global ----
    if (tid < NPT / 4) {
        *(int4*)&ij[tid * 4] = ((const int4*)ijg)[tid];
    }
    // ---- per-lane epilogue constants (indexed by col) ----
    float wbr[8], hr[8];
#pragma unroll
    for (int n = 0; n < 8; ++n) {
        wbr[n] = wbg[n * 16 + col];
        hr[n]  = hg[n * 16 + col];
    }
    // ---- W B-fragments into registers (one-time, from L2-resident bf16 copy) ----
    short8 bfrag[8][4];
#pragma unroll
    for (int n = 0; n < 8; ++n)
#pragma unroll
        for (int k = 0; k < 4; ++k)
            bfrag[n][k] = *(const short8*)(wbf + (n * 16 + col) * NE + k * 32 + quad * 8);
    __syncthreads();

    // ---- main MFMA loop: S[p,a] = sum_e hp[p,e] * W[a,e] + wb[a] ----
    for (int mt = wid; mt < NMT; mt += 4) {
        const int p0 = mt * 16;
        const int v  = ij[p0 + col];          // A-row p0+col -> fields (i,j)
        const float* xip = &xs[(v >> 8) & 255][0];
        const float* xjp = &xs[v & 255][0];

        floatx4 acc[8];
#pragma unroll
        for (int n = 0; n < 8; ++n)
            acc[n] = (floatx4){wbr[n], wbr[n], wbr[n], wbr[n]};  // bias folded into C-init

#pragma unroll
        for (int k = 0; k < 4; ++k) {
            const int koff = k * 32 + quad * 8;
            float4 i0 = *(const float4*)(xip + koff);
            float4 i1 = *(const float4*)(xip + koff + 4);
            float4 j0 = *(const float4*)(xjp + koff);
            float4 j1 = *(const float4*)(xjp + koff + 4);
            union { short8 s; unsigned u[4]; } af;
            af.u[0] = cvt_pk_bf16(i0.x * j0.x, i0.y * j0.y);
            af.u[1] = cvt_pk_bf16(i0.z * j0.z, i0.w * j0.w);
            af.u[2] = cvt_pk_bf16(i1.x * j1.x, i1.y * j1.y);
            af.u[3] = cvt_pk_bf16(i1.z * j1.z, i1.w * j1.w);
#pragma unroll
            for (int n = 0; n < 8; ++n)
                acc[n] = __builtin_amdgcn_mfma_f32_16x16x32_bf16(af.s, bfrag[n][k], acc[n], 0, 0, 0);
        }

        // scores[p] = sum_a relu(S[p,a]) * h[a]   (h_b cancels in softmax)
        float ps[4] = {0.f, 0.f, 0.f, 0.f};
#pragma unroll
        for (int n = 0; n < 8; ++n) {
#pragma unroll
            for (int r = 0; r < 4; ++r)
                ps[r] += fmaxf(acc[n][r], 0.f) * hr[n];
        }
#pragma unroll
        for (int r = 0; r < 4; ++r) ps[r] = rowsum16(ps[r]);
        if (col == 0) {
#pragma unroll
            for (int r = 0; r < 4; ++r) {
                int p = p0 + quad * 4 + r;
                if (p < NP) sc[p] = ps[r];
            }
        }
    }
    __syncthreads();

    // ---- softmax over 780 pairs (unnormalized exp; fold 1/sum at the end) ----
    float m = -1e30f;
    for (int p = tid; p < NP; p += 256) m = fmaxf(m, sc[p]);
#pragma unroll
    for (int off = 1; off < 64; off <<= 1) m = fmaxf(m, __shfl_xor(m, off));
    if (lane == 0) red_max[wid] = m;
    __syncthreads();
    const float M = fmaxf(fmaxf(red_max[0], red_max[1]), fmaxf(red_max[2], red_max[3]));

    float s = 0.f;
    for (int p = tid; p < NPT; p += 256) {          // extend to NPT: zero-pad tail
        float e = (p < NP) ? __expf(sc[p] - M) : 0.f;
        sc[p] = e;
        s += e;
    }
#pragma unroll
    for (int off = 1; off < 64; off <<= 1) s += __shfl_xor(s, off);
    if (lane == 0) red_sum[wid] = s;
    __syncthreads();   // exp values visible; red_sum written

    // ---- afm[e] = sum_p exp_p * x[i_p,e] * x[j_p,e]  (fp32) ----
    // 4-pair-unrolled batch loop: int4 ij + float4 sc broadcast + 8 independent b64 reads
    {
        const int e2   = lane * 2;            // 2 consecutive e per lane
        const int pbeg = wid * 196;           // 784/4 waves = 196 pairs per wave
        float a0 = 0.f, a1 = 0.f;
        for (int p = pbeg; p < pbeg + 196; p += 4) {
            int4   v4 = *(const int4*)&ij[p];
            float4 w4 = *(const float4*)&sc[p];
            float2 i0 = *(const float2*)&xs[(v4.x >> 8) & 255][e2];
            float2 j0 = *(const float2*)&xs[v4.x & 255][e2];
            float2 i1 = *(const float2*)&xs[(v4.y >> 8) & 255][e2];
            float2 j1 = *(const float2*)&xs[v4.y & 255][e2];
            float2 i2 = *(const float2*)&xs[(v4.z >> 8) & 255][e2];
            float2 j2 = *(const float2*)&xs[v4.z & 255][e2];
            float2 i3 = *(const float2*)&xs[(v4.w >> 8) & 255][e2];
            float2 j3 = *(const float2*)&xs[v4.w & 255][e2];
            a0 += w4.x * i0.x * j0.x;  a1 += w4.x * i0.y * j0.y;
            a0 += w4.y * i1.x * j1.x;  a1 += w4.y * i1.y * j1.y;
            a0 += w4.z * i2.x * j2.x;  a1 += w4.z * i2.y * j2.y;
            a0 += w4.w * i3.x * j3.x;  a1 += w4.w * i3.y * j3.y;
        }
        *(float2*)&afmp[wid][e2] = make_float2(a0, a1);
    }
    __syncthreads();

    // ---- out[b] = (sum_e afm_un[e] * pw[e]) / sum_exp + p_b ----
    float vv = 0.f;
    if (tid < NE) {
        float a = afmp[0][tid] + afmp[1][tid] + afmp[2][tid] + afmp[3][tid];
        vv = a * pwg[tid];
    }
#pragma unroll
    for (int off = 1; off < 64; off <<= 1) vv += __shfl_xor(vv, off);
    if (lane == 0) red_out[wid] = vv;
    __syncthreads();
    if (tid == 0) {
        float S   = red_sum[0] + red_sum[1] + red_sum[2] + red_sum[3];
        float tot = red_out[0] + red_out[1] + red_out[2] + red_out[3];
        out[b] = tot / S + pbg[0];
    }
}

extern "C" void kernel_launch(void* const* d_in, const int* in_sizes, int n_in,
                              void* d_out, int out_size, void* d_ws, size_t ws_size,
                              hipStream_t stream) {
    const float* xg  = (const float*)d_in[0];  // x [B,F,E]
    const float* wg  = (const float*)d_in[1];  // attn_w_w [A,E]
    const float* wbg = (const float*)d_in[2];  // attn_w_b [A]
    const float* hg  = (const float*)d_in[3];  // attn_h_w [1,A]
    // d_in[4] = attn_h_b : constant shift, cancels in softmax
    const float* pwg = (const float*)d_in[5];  // attn_p_w [1,E]
    const float* pbg = (const float*)d_in[6];  // attn_p_b [1]
    const int B = in_sizes[0] / (NF * NE);

    unsigned short* wbf = (unsigned short*)d_ws;                        // 32768 B
    int* ijg = (int*)((char*)d_ws + NA * NE * sizeof(unsigned short));  // 3136 B

    afm_prep_kernel<<<16, 256, 0, stream>>>(wg, wbf, ijg);
    afm_fused_kernel<<<B, 256, 0, stream>>>(xg, wbf, ijg, wbg, hg, pwg, pbg, (float*)d_out);
}

// Round 5
// 257.585 us; speedup vs baseline: 1.0838x; 1.0838x over previous
//
#include <hip/hip_runtime.h>

#define NF 40
#define NE 128
#define NA 128
#define NP 780        // NF*(NF-1)/2
#define NPT 784       // padded to 49*16
#define NMT 49        // m-tiles of 16 pairs
#define XS_LD 132     // x LDS row stride (floats): 16B aligned, spreads banks
#define G_LD 44       // G row stride (floats): multiple of 4 -> 16B-aligned float4 rows

typedef short short8 __attribute__((ext_vector_type(8)));
typedef float floatx4 __attribute__((ext_vector_type(4)));

__device__ __forceinline__ unsigned cvt_pk_bf16(float lo, float hi) {
    // D[15:0] = bf16(S0), D[31:16] = bf16(S1), RNE
    unsigned r;
    asm("v_cvt_pk_bf16_f32 %0, %1, %2" : "=v"(r) : "v"(lo), "v"(hi));
    return r;
}

// sum across each 16-lane row via DPP row_ror (VALU pipe, no DS traffic)
__device__ __forceinline__ float rowsum16(float x) {
    x += __int_as_float(__builtin_amdgcn_update_dpp(0, __float_as_int(x), 0x121, 0xf, 0xf, true)); // ror:1
    x += __int_as_float(__builtin_amdgcn_update_dpp(0, __float_as_int(x), 0x122, 0xf, 0xf, true)); // ror:2
    x += __int_as_float(__builtin_amdgcn_update_dpp(0, __float_as_int(x), 0x124, 0xf, 0xf, true)); // ror:4
    x += __int_as_float(__builtin_amdgcn_update_dpp(0, __float_as_int(x), 0x128, 0xf, 0xf, true)); // ror:8
    return x;
}

// ---- prep: W fp32 -> bf16 into workspace; pair-index table into workspace ----
__global__ __launch_bounds__(256)
void afm_prep_kernel(const float* __restrict__ wg,
                     unsigned short* __restrict__ wbf,
                     int* __restrict__ ijg)
{
    const int t = blockIdx.x * 256 + threadIdx.x;   // 4096 threads
    if (t < NA * NE / 4) {
        float4 v = *(const float4*)(wg + t * 4);
        uint2 pk;
        pk.x = cvt_pk_bf16(v.x, v.y);
        pk.y = cvt_pk_bf16(v.z, v.w);
        *(uint2*)(wbf + t * 4) = pk;
    }
    if (t < NPT) {
        int v = 0;
        if (t < NP) {
            int i = 0, rem = t;
            while (rem >= (NF - 1 - i)) { rem -= (NF - 1 - i); ++i; }
            v = (i << 8) | (i + 1 + rem);
        }
        ijg[t] = v;
    }
}

__global__ __launch_bounds__(256, 3)
void afm_fused_kernel(const float* __restrict__ xg,          // [B, F, E]
                      const unsigned short* __restrict__ wbf,// [A, E] bf16 (prepped)
                      const int* __restrict__ ijg,           // [NPT] packed (i<<8)|j
                      const float* __restrict__ wbg,         // [A]
                      const float* __restrict__ hg,          // [1, A]
                      const float* __restrict__ pwg,         // [1, E]
                      const float* __restrict__ pbg,         // [1]
                      float* __restrict__ out)               // [B]
{
    __shared__ float xs[NF][XS_LD];          // 21120 B fp32 x
    __shared__ float sc[NPT];                // 3136 B scores -> exp (zero-padded to NPT)
    __shared__ int   ij[NPT];                // 3136 B packed (i<<8)|j (0 for p>=NP)
    __shared__ float G[NF][G_LD];            // 7040 B symmetric exp-weight matrix
    __shared__ float afmp[4][NE];            // 2048 B afm partials (per wave)
    __shared__ float red_max[4], red_sum[4], red_out[4];

    const int tid  = threadIdx.x;
    const int b    = blockIdx.x;
    const int lane = tid & 63;
    const int wid  = tid >> 6;
    const int col  = lane & 15;
    const int quad = (lane >> 4) & 3;

    // ---- stage x[b] (fp32) ----
    const float* xb = xg + (size_t)b * (NF * NE);
    for (int t = tid; t < NF * (NE / 4); t += 256) {
        int row = t >> 5, c = (t & 31) * 4;
        float4 v = *(const float4*)(xb + row * NE + c);
        *(float4*)&xs[row][c] = v;
    }
    // ---- pair index table: copy from prepped global ----
    if (tid < NPT / 4) {
        *(int4*)&ij[tid * 4] = ((const int4*)ijg)[tid];
    }
    // ---- per-lane epilogue constants (indexed by col) ----
    float wbr[8], hr[8];
#pragma unroll
    for (int n = 0; n < 8; ++n) {
        wbr[n] = wbg[n * 16 + col];
        hr[n]  = hg[n * 16 + col];
    }
    // ---- W B-fragments into registers (one-time, from L2-resident bf16 copy) ----
    short8 bfrag[8][4];
#pragma unroll
    for (int n = 0; n < 8; ++n)
#pragma unroll
        for (int k = 0; k < 4; ++k)
            bfrag[n][k] = *(const short8*)(wbf + (n * 16 + col) * NE + k * 32 + quad * 8);
    __syncthreads();

    // ---- main MFMA loop: S[p,a] = sum_e hp[p,e] * W[a,e] + wb[a] ----
    for (int mt = wid; mt < NMT; mt += 4) {
        const int p0 = mt * 16;
        const int v  = ij[p0 + col];          // A-row p0+col -> fields (i,j)
        const float* xip = &xs[(v >> 8) & 255][0];
        const float* xjp = &xs[v & 255][0];

        floatx4 acc[8];
#pragma unroll
        for (int n = 0; n < 8; ++n)
            acc[n] = (floatx4){wbr[n], wbr[n], wbr[n], wbr[n]};  // bias folded into C-init

#pragma unroll
        for (int k = 0; k < 4; ++k) {
            const int koff = k * 32 + quad * 8;
            float4 i0 = *(const float4*)(xip + koff);
            float4 i1 = *(const float4*)(xip + koff + 4);
            float4 j0 = *(const float4*)(xjp + koff);
            float4 j1 = *(const float4*)(xjp + koff + 4);
            union { short8 s; unsigned u[4]; } af;
            af.u[0] = cvt_pk_bf16(i0.x * j0.x, i0.y * j0.y);
            af.u[1] = cvt_pk_bf16(i0.z * j0.z, i0.w * j0.w);
            af.u[2] = cvt_pk_bf16(i1.x * j1.x, i1.y * j1.y);
            af.u[3] = cvt_pk_bf16(i1.z * j1.z, i1.w * j1.w);
#pragma unroll
            for (int n = 0; n < 8; ++n)
                acc[n] = __builtin_amdgcn_mfma_f32_16x16x32_bf16(af.s, bfrag[n][k], acc[n], 0, 0, 0);
        }

        // scores[p] = sum_a relu(S[p,a]) * h[a]   (h_b cancels in softmax)
        float ps[4] = {0.f, 0.f, 0.f, 0.f};
#pragma unroll
        for (int n = 0; n < 8; ++n) {
#pragma unroll
            for (int r = 0; r < 4; ++r)
                ps[r] += fmaxf(acc[n][r], 0.f) * hr[n];
        }
#pragma unroll
        for (int r = 0; r < 4; ++r) ps[r] = rowsum16(ps[r]);
        if (col == 0) {
#pragma unroll
            for (int r = 0; r < 4; ++r) {
                int p = p0 + quad * 4 + r;
                if (p < NP) sc[p] = ps[r];
            }
        }
    }
    __syncthreads();

    // ---- softmax over 780 pairs (unnormalized exp; fold 1/sum at the end) ----
    float m = -1e30f;
    for (int p = tid; p < NP; p += 256) m = fmaxf(m, sc[p]);
#pragma unroll
    for (int off = 1; off < 64; off <<= 1) m = fmaxf(m, __shfl_xor(m, off));
    if (lane == 0) red_max[wid] = m;
    __syncthreads();
    const float M = fmaxf(fmaxf(red_max[0], red_max[1]), fmaxf(red_max[2], red_max[3]));

    float s = 0.f;
    for (int p = tid; p < NPT; p += 256) {          // extend to NPT: zero-pad tail
        float e = (p < NP) ? __expf(sc[p] - M) : 0.f;
        sc[p] = e;
        s += e;
    }
#pragma unroll
    for (int off = 1; off < 64; off <<= 1) s += __shfl_xor(s, off);
    if (lane == 0) red_sum[wid] = s;
    __syncthreads();   // exp values visible; red_sum written

    // ---- build symmetric weight matrix G[i][j] = exp_w(pair(i,j)), diag 0 ----
    for (int p = tid; p < NP; p += 256) {
        int v = ij[p];
        float w = sc[p];
        G[(v >> 8) & 255][v & 255] = w;
        G[v & 255][(v >> 8) & 255] = w;
    }
    if (tid < NF) G[tid][tid] = 0.f;
    __syncthreads();

    // ---- afm[e] = 0.5 * sum_i x[i,e] * (G x)[i,e]  (fp32) ----
    // each wave owns 10 i-rows, lanes own 2 consecutive e; x columns in regs
    {
        const int e2 = lane * 2;
        float2 xc[NF];
#pragma unroll
        for (int j = 0; j < NF; ++j) xc[j] = *(const float2*)&xs[j][e2];

        float a0 = 0.f, a1 = 0.f;
#pragma unroll
        for (int ii = 0; ii < 10; ++ii) {
            const int i = wid * 10 + ii;
            float y0 = 0.f, y1 = 0.f;
#pragma unroll
            for (int jj = 0; jj < 10; ++jj) {
                float4 g = *(const float4*)&G[i][jj * 4];   // wave-uniform broadcast
                y0 += g.x * xc[jj * 4 + 0].x;  y1 += g.x * xc[jj * 4 + 0].y;
                y0 += g.y * xc[jj * 4 + 1].x;  y1 += g.y * xc[jj * 4 + 1].y;
                y0 += g.z * xc[jj * 4 + 2].x;  y1 += g.z * xc[jj * 4 + 2].y;
                y0 += g.w * xc[jj * 4 + 3].x;  y1 += g.w * xc[jj * 4 + 3].y;
            }
            float2 xi = *(const float2*)&xs[i][e2];         // LDS read: keeps xc[] statically indexed
            a0 += xi.x * y0;
            a1 += xi.y * y1;
        }
        *(float2*)&afmp[wid][e2] = make_float2(a0 * 0.5f, a1 * 0.5f);
    }
    __syncthreads();

    // ---- out[b] = (sum_e afm_un[e] * pw[e]) / sum_exp + p_b ----
    float vv = 0.f;
    if (tid < NE) {
        float a = afmp[0][tid] + afmp[1][tid] + afmp[2][tid] + afmp[3][tid];
        vv = a * pwg[tid];
    }
#pragma unroll
    for (int off = 1; off < 64; off <<= 1) vv += __shfl_xor(vv, off);
    if (lane == 0) red_out[wid] = vv;
    __syncthreads();
    if (tid == 0) {
        float S   = red_sum[0] + red_sum[1] + red_sum[2] + red_sum[3];
        float tot = red_out[0] + red_out[1] + red_out[2] + red_out[3];
        out[b] = tot / S + pbg[0];
    }
}

extern "C" void kernel_launch(void* const* d_in, const int* in_sizes, int n_in,
                              void* d_out, int out_size, void* d_ws, size_t ws_size,
                              hipStream_t stream) {
    const float* xg  = (const float*)d_in[0];  // x [B,F,E]
    const float* wg  = (const float*)d_in[1];  // attn_w_w [A,E]
    const float* wbg = (const float*)d_in[2];  // attn_w_b [A]
    const float* hg  = (const float*)d_in[3];  // attn_h_w [1,A]
    // d_in[4] = attn_h_b : constant shift, cancels in softmax
    const float* pwg = (const float*)d_in[5];  // attn_p_w [1,E]
    const float* pbg = (const float*)d_in[6];  // attn_p_b [1]
    const int B = in_sizes[0] / (NF * NE);

    unsigned short* wbf = (unsigned short*)d_ws;                        // 32768 B
    int* ijg = (int*)((char*)d_ws + NA * NE * sizeof(unsigned short));  // 3136 B

    afm_prep_kernel<<<16, 256, 0, stream>>>(wg, wbf, ijg);
    afm_fused_kernel<<<B, 256, 0, stream>>>(xg, wbf, ijg, wbg, hg, pwg, pbg, (float*)d_out);
}

// Round 6
// 122.422 us; speedup vs baseline: 2.2804x; 2.1041x over previous
//
#include <hip/hip_runtime.h>

#define NF 40
#define NE 128
#define NA 128
#define NP 780        // NF*(NF-1)/2
#define NPT 784       // padded to 49*16
#define NMT 49        // m-tiles of 16 pairs
#define XS_LD 132     // x LDS row stride (floats): 16B aligned, spreads banks
#define G_LD 44       // G row stride (floats): multiple of 4 -> 16B-aligned float4 rows

typedef short short8 __attribute__((ext_vector_type(8)));
typedef float floatx4 __attribute__((ext_vector_type(4)));

__device__ __forceinline__ unsigned cvt_pk_bf16(float lo, float hi) {
    // D[15:0] = bf16(S0), D[31:16] = bf16(S1), RNE
    unsigned r;
    asm("v_cvt_pk_bf16_f32 %0, %1, %2" : "=v"(r) : "v"(lo), "v"(hi));
    return r;
}

// sum across each 16-lane row via DPP row_ror (VALU pipe, no DS traffic)
__device__ __forceinline__ float rowsum16(float x) {
    x += __int_as_float(__builtin_amdgcn_update_dpp(0, __float_as_int(x), 0x121, 0xf, 0xf, true)); // ror:1
    x += __int_as_float(__builtin_amdgcn_update_dpp(0, __float_as_int(x), 0x122, 0xf, 0xf, true)); // ror:2
    x += __int_as_float(__builtin_amdgcn_update_dpp(0, __float_as_int(x), 0x124, 0xf, 0xf, true)); // ror:4
    x += __int_as_float(__builtin_amdgcn_update_dpp(0, __float_as_int(x), 0x128, 0xf, 0xf, true)); // ror:8
    return x;
}

// ---- prep: W fp32 -> bf16 into workspace; pair-index table into workspace ----
__global__ __launch_bounds__(256)
void afm_prep_kernel(const float* __restrict__ wg,
                     unsigned short* __restrict__ wbf,
                     int* __restrict__ ijg)
{
    const int t = blockIdx.x * 256 + threadIdx.x;   // 4096 threads
    if (t < NA * NE / 4) {
        float4 v = *(const float4*)(wg + t * 4);
        uint2 pk;
        pk.x = cvt_pk_bf16(v.x, v.y);
        pk.y = cvt_pk_bf16(v.z, v.w);
        *(uint2*)(wbf + t * 4) = pk;
    }
    if (t < NPT) {
        int v = 0;
        if (t < NP) {
            int i = 0, rem = t;
            while (rem >= (NF - 1 - i)) { rem -= (NF - 1 - i); ++i; }
            v = (i << 8) | (i + 1 + rem);
        }
        ijg[t] = v;
    }
}

__global__ __launch_bounds__(256, 2)
void afm_fused_kernel(const float* __restrict__ xg,          // [B, F, E]
                      const unsigned short* __restrict__ wbf,// [A, E] bf16 (prepped)
                      const int* __restrict__ ijg,           // [NPT] packed (i<<8)|j
                      const float* __restrict__ wbg,         // [A]
                      const float* __restrict__ hg,          // [1, A]
                      const float* __restrict__ pwg,         // [1, E]
                      const float* __restrict__ pbg,         // [1]
                      float* __restrict__ out)               // [B]
{
    __shared__ float xs[NF][XS_LD];          // 21120 B fp32 x
    __shared__ float sc[NPT];                // 3136 B scores -> exp
    __shared__ int   ij[NPT];                // 3136 B packed (i<<8)|j (0 for p>=NP)
    __shared__ float G[NF][G_LD];            // 7040 B symmetric exp-weight matrix
    __shared__ float afmp[4][NE];            // 2048 B afm partials (per wave)
    __shared__ float red_max[4], red_sum[4], red_out[4];

    const int tid  = threadIdx.x;
    const int b    = blockIdx.x;
    const int lane = tid & 63;
    const int wid  = tid >> 6;
    const int col  = lane & 15;
    const int quad = (lane >> 4) & 3;

    // ---- stage x[b] (fp32) ----
    const float* xb = xg + (size_t)b * (NF * NE);
    for (int t = tid; t < NF * (NE / 4); t += 256) {
        int row = t >> 5, c = (t & 31) * 4;
        float4 v = *(const float4*)(xb + row * NE + c);
        *(float4*)&xs[row][c] = v;
    }
    // ---- pair index table: copy from prepped global ----
    if (tid < NPT / 4) {
        *(int4*)&ij[tid * 4] = ((const int4*)ijg)[tid];
    }
    // ---- per-lane epilogue constants (indexed by col) ----
    float wbr[8], hr[8];
#pragma unroll
    for (int n = 0; n < 8; ++n) {
        wbr[n] = wbg[n * 16 + col];
        hr[n]  = hg[n * 16 + col];
    }
    // ---- W B-fragments into registers (one-time, from L2-resident bf16 copy) ----
    short8 bfrag[8][4];
#pragma unroll
    for (int n = 0; n < 8; ++n)
#pragma unroll
        for (int k = 0; k < 4; ++k)
            bfrag[n][k] = *(const short8*)(wbf + (n * 16 + col) * NE + k * 32 + quad * 8);
    __syncthreads();

    // ---- main MFMA loop: S[p,a] = sum_e hp[p,e] * W[a,e] + wb[a] ----
    for (int mt = wid; mt < NMT; mt += 4) {
        const int p0 = mt * 16;
        const int v  = ij[p0 + col];          // A-row p0+col -> fields (i,j)
        const float* xip = &xs[(v >> 8) & 255][0];
        const float* xjp = &xs[v & 255][0];

        floatx4 acc[8];
#pragma unroll
        for (int n = 0; n < 8; ++n)
            acc[n] = (floatx4){wbr[n], wbr[n], wbr[n], wbr[n]};  // bias folded into C-init

#pragma unroll
        for (int k = 0; k < 4; ++k) {
            const int koff = k * 32 + quad * 8;
            float4 i0 = *(const float4*)(xip + koff);
            float4 i1 = *(const float4*)(xip + koff + 4);
            float4 j0 = *(const float4*)(xjp + koff);
            float4 j1 = *(const float4*)(xjp + koff + 4);
            union { short8 s; unsigned u[4]; } af;
            af.u[0] = cvt_pk_bf16(i0.x * j0.x, i0.y * j0.y);
            af.u[1] = cvt_pk_bf16(i0.z * j0.z, i0.w * j0.w);
            af.u[2] = cvt_pk_bf16(i1.x * j1.x, i1.y * j1.y);
            af.u[3] = cvt_pk_bf16(i1.z * j1.z, i1.w * j1.w);
#pragma unroll
            for (int n = 0; n < 8; ++n)
                acc[n] = __builtin_amdgcn_mfma_f32_16x16x32_bf16(af.s, bfrag[n][k], acc[n], 0, 0, 0);
        }

        // scores[p] = sum_a relu(S[p,a]) * h[a]   (h_b cancels in softmax)
        float ps[4] = {0.f, 0.f, 0.f, 0.f};
#pragma unroll
        for (int n = 0; n < 8; ++n) {
#pragma unroll
            for (int r = 0; r < 4; ++r)
                ps[r] += fmaxf(acc[n][r], 0.f) * hr[n];
        }
#pragma unroll
        for (int r = 0; r < 4; ++r) ps[r] = rowsum16(ps[r]);
        if (col == 0) {
#pragma unroll
            for (int r = 0; r < 4; ++r) {
                int p = p0 + quad * 4 + r;
                if (p < NP) sc[p] = ps[r];
            }
        }
    }
    __syncthreads();

    // ---- softmax over 780 pairs (unnormalized exp; fold 1/sum at the end) ----
    float m = -1e30f;
    for (int p = tid; p < NP; p += 256) m = fmaxf(m, sc[p]);
#pragma unroll
    for (int off = 1; off < 64; off <<= 1) m = fmaxf(m, __shfl_xor(m, off));
    if (lane == 0) red_max[wid] = m;
    __syncthreads();
    const float M = fmaxf(fmaxf(red_max[0], red_max[1]), fmaxf(red_max[2], red_max[3]));

    float s = 0.f;
    for (int p = tid; p < NP; p += 256) {
        float e = __expf(sc[p] - M);
        sc[p] = e;
        s += e;
    }
#pragma unroll
    for (int off = 1; off < 64; off <<= 1) s += __shfl_xor(s, off);
    if (lane == 0) red_sum[wid] = s;
    __syncthreads();   // exp values visible; red_sum written

    // ---- build symmetric weight matrix G[i][j] = exp_w(pair(i,j)), diag 0 ----
    for (int p = tid; p < NP; p += 256) {
        int v = ij[p];
        float w = sc[p];
        G[(v >> 8) & 255][v & 255] = w;
        G[v & 255][(v >> 8) & 255] = w;
    }
    if (tid < NF) G[tid][tid] = 0.f;
    __syncthreads();

    // ---- afm[e] = 0.5 * sum_i x[i,e] * (G x)[i,e]  (fp32) ----
    // each wave owns 10 i-rows, lanes own 2 consecutive e; x columns in regs
    {
        const int e2 = lane * 2;
        float2 xc[NF];
#pragma unroll
        for (int j = 0; j < NF; ++j) xc[j] = *(const float2*)&xs[j][e2];

        float a0 = 0.f, a1 = 0.f;
#pragma unroll
        for (int ii = 0; ii < 10; ++ii) {
            const int i = wid * 10 + ii;
            float y0 = 0.f, y1 = 0.f;
#pragma unroll
            for (int jj = 0; jj < 10; ++jj) {
                float4 g = *(const float4*)&G[i][jj * 4];   // wave-uniform broadcast
                y0 += g.x * xc[jj * 4 + 0].x;  y1 += g.x * xc[jj * 4 + 0].y;
                y0 += g.y * xc[jj * 4 + 1].x;  y1 += g.y * xc[jj * 4 + 1].y;
                y0 += g.z * xc[jj * 4 + 2].x;  y1 += g.z * xc[jj * 4 + 2].y;
                y0 += g.w * xc[jj * 4 + 3].x;  y1 += g.w * xc[jj * 4 + 3].y;
            }
            float2 xi = *(const float2*)&xs[i][e2];         // LDS read: keeps xc[] statically indexed
            a0 += xi.x * y0;
            a1 += xi.y * y1;
        }
        *(float2*)&afmp[wid][e2] = make_float2(a0 * 0.5f, a1 * 0.5f);
    }
    __syncthreads();

    // ---- out[b] = (sum_e afm_un[e] * pw[e]) / sum_exp + p_b ----
    float vv = 0.f;
    if (tid < NE) {
        float a = afmp[0][tid] + afmp[1][tid] + afmp[2][tid] + afmp[3][tid];
        vv = a * pwg[tid];
    }
#pragma unroll
    for (int off = 1; off < 64; off <<= 1) vv += __shfl_xor(vv, off);
    if (lane == 0) red_out[wid] = vv;
    __syncthreads();
    if (tid == 0) {
        float S   = red_sum[0] + red_sum[1] + red_sum[2] + red_sum[3];
        float tot = red_out[0] + red_out[1] + red_out[2] + red_out[3];
        out[b] = tot / S + pbg[0];
    }
}

extern "C" void kernel_launch(void* const* d_in, const int* in_sizes, int n_in,
                              void* d_out, int out_size, void* d_ws, size_t ws_size,
                              hipStream_t stream) {
    const float* xg  = (const float*)d_in[0];  // x [B,F,E]
    const float* wg  = (const float*)d_in[1];  // attn_w_w [A,E]
    const float* wbg = (const float*)d_in[2];  // attn_w_b [A]
    const float* hg  = (const float*)d_in[3];  // attn_h_w [1,A]
    // d_in[4] = attn_h_b : constant shift, cancels in softmax
    const float* pwg = (const float*)d_in[5];  // attn_p_w [1,E]
    const float* pbg = (const float*)d_in[6];  // attn_p_b [1]
    const int B = in_sizes[0] / (NF * NE);

    unsigned short* wbf = (unsigned short*)d_ws;                        // 32768 B
    int* ijg = (int*)((char*)d_ws + NA * NE * sizeof(unsigned short));  // 3136 B

    afm_prep_kernel<<<16, 256, 0, stream>>>(wg, wbf, ijg);
    afm_fused_kernel<<<B, 256, 0, stream>>>(xg, wbf, ijg, wbg, hg, pwg, pbg, (float*)d_out);
}

// Round 7
// 120.175 us; speedup vs baseline: 2.3230x; 1.0187x over previous
//
#include <hip/hip_runtime.h>
#include <hip/hip_fp16.h>

#define NF 40
#define NE 128
#define NA 128
#define NP 780        // NF*(NF-1)/2
#define NPT 784       // padded to 49*16
#define NMT 49        // m-tiles of 16 pairs
#define XS_LD 132     // fp32 x LDS row stride (floats): 16B aligned, spreads banks
#define XS16_LD 136   // f16 x LDS row stride (ushorts): 272B rows, 16B aligned
#define G_LD 44       // G row stride (floats): multiple of 4 -> 16B-aligned float4 rows

typedef _Float16 half8 __attribute__((ext_vector_type(8)));
typedef float floatx4 __attribute__((ext_vector_type(4)));

// sum across each 16-lane row via DPP row_ror (VALU pipe, no DS traffic)
__device__ __forceinline__ float rowsum16(float x) {
    x += __int_as_float(__builtin_amdgcn_update_dpp(0, __float_as_int(x), 0x121, 0xf, 0xf, true)); // ror:1
    x += __int_as_float(__builtin_amdgcn_update_dpp(0, __float_as_int(x), 0x122, 0xf, 0xf, true)); // ror:2
    x += __int_as_float(__builtin_amdgcn_update_dpp(0, __float_as_int(x), 0x124, 0xf, 0xf, true)); // ror:4
    x += __int_as_float(__builtin_amdgcn_update_dpp(0, __float_as_int(x), 0x128, 0xf, 0xf, true)); // ror:8
    return x;
}

// ---- prep: W fp32 -> f16 (RNE) into workspace; pair-index table into workspace ----
__global__ __launch_bounds__(256)
void afm_prep_kernel(const float* __restrict__ wg,
                     unsigned short* __restrict__ wbf,
                     int* __restrict__ ijg)
{
    const int t = blockIdx.x * 256 + threadIdx.x;   // 4096 threads
    if (t < NA * NE / 4) {
        float4 v = *(const float4*)(wg + t * 4);
        union { _Float16 h[4]; ushort4 u; } c;
        c.h[0] = (_Float16)v.x;
        c.h[1] = (_Float16)v.y;
        c.h[2] = (_Float16)v.z;
        c.h[3] = (_Float16)v.w;
        *(ushort4*)(wbf + t * 4) = c.u;
    }
    if (t < NPT) {
        int v = 0;
        if (t < NP) {
            int i = 0, rem = t;
            while (rem >= (NF - 1 - i)) { rem -= (NF - 1 - i); ++i; }
            v = (i << 8) | (i + 1 + rem);
        }
        ijg[t] = v;
    }
}

__global__ __launch_bounds__(256, 2)
void afm_fused_kernel(const float* __restrict__ xg,          // [B, F, E]
                      const unsigned short* __restrict__ wbf,// [A, E] f16 (prepped)
                      const int* __restrict__ ijg,           // [NPT] packed (i<<8)|j
                      const float* __restrict__ wbg,         // [A]
                      const float* __restrict__ hg,          // [1, A]
                      const float* __restrict__ pwg,         // [1, E]
                      const float* __restrict__ pbg,         // [1]
                      float* __restrict__ out)               // [B]
{
    __shared__ float          xs[NF][XS_LD];      // 21120 B fp32 x (softmax/afm path)
    __shared__ unsigned short xs16[NF][XS16_LD];  // 10880 B f16 x (MFMA path)
    __shared__ float sc[NPT];                     // 3136 B scores -> exp
    __shared__ int   ij[NPT];                     // 3136 B packed (i<<8)|j (0 for p>=NP)
    __shared__ float G[NF][G_LD];                 // 7040 B symmetric exp-weight matrix
    __shared__ float afmp[4][NE];                 // 2048 B afm partials (per wave)
    __shared__ float red_max[4], red_sum[4], red_out[4];

    const int tid  = threadIdx.x;
    const int b    = blockIdx.x;
    const int lane = tid & 63;
    const int wid  = tid >> 6;
    const int col  = lane & 15;
    const int quad = (lane >> 4) & 3;

    // ---- stage x[b]: fp32 copy + f16 copy ----
    const float* xb = xg + (size_t)b * (NF * NE);
    for (int t = tid; t < NF * (NE / 4); t += 256) {
        int row = t >> 5, c = (t & 31) * 4;
        float4 v = *(const float4*)(xb + row * NE + c);
        *(float4*)&xs[row][c] = v;
        union { _Float16 h[4]; unsigned long long ull; } cv;
        cv.h[0] = (_Float16)v.x;
        cv.h[1] = (_Float16)v.y;
        cv.h[2] = (_Float16)v.z;
        cv.h[3] = (_Float16)v.w;
        *(unsigned long long*)&xs16[row][c] = cv.ull;   // 8B store, 8B aligned
    }
    // ---- pair index table: copy from prepped global ----
    if (tid < NPT / 4) {
        *(int4*)&ij[tid * 4] = ((const int4*)ijg)[tid];
    }
    // ---- per-lane epilogue constants (indexed by col) ----
    float wbr[8], hr[8];
#pragma unroll
    for (int n = 0; n < 8; ++n) {
        wbr[n] = wbg[n * 16 + col];
        hr[n]  = hg[n * 16 + col];
    }
    // ---- W B-fragments into registers (one-time, from L2-resident f16 copy) ----
    half8 bfrag[8][4];
#pragma unroll
    for (int n = 0; n < 8; ++n)
#pragma unroll
        for (int k = 0; k < 4; ++k)
            bfrag[n][k] = *(const half8*)(const void*)(wbf + (n * 16 + col) * NE + k * 32 + quad * 8);
    __syncthreads();

    // ---- main MFMA loop: S[p,a] = sum_e hp[p,e] * W[a,e] + wb[a] ----
    for (int mt = wid; mt < NMT; mt += 4) {
        const int p0 = mt * 16;
        const int v  = ij[p0 + col];          // A-row p0+col -> fields (i,j)
        const unsigned short* xi16 = &xs16[(v >> 8) & 255][0];
        const unsigned short* xj16 = &xs16[v & 255][0];

        floatx4 acc[8];
#pragma unroll
        for (int n = 0; n < 8; ++n)
            acc[n] = (floatx4){wbr[n], wbr[n], wbr[n], wbr[n]};  // bias folded into C-init

#pragma unroll
        for (int k = 0; k < 4; ++k) {
            const int koff = k * 32 + quad * 8;
            half8 ih = *(const half8*)(const void*)(xi16 + koff);   // one b128 per operand
            half8 jh = *(const half8*)(const void*)(xj16 + koff);
            half8 af = ih * jh;                                     // 4x v_pk_mul_f16
#pragma unroll
            for (int n = 0; n < 8; ++n)
                acc[n] = __builtin_amdgcn_mfma_f32_16x16x32_f16(af, bfrag[n][k], acc[n], 0, 0, 0);
        }

        // scores[p] = sum_a relu(S[p,a]) * h[a]   (h_b cancels in softmax)
        float ps[4] = {0.f, 0.f, 0.f, 0.f};
#pragma unroll
        for (int n = 0; n < 8; ++n) {
#pragma unroll
            for (int r = 0; r < 4; ++r)
                ps[r] += fmaxf(acc[n][r], 0.f) * hr[n];
        }
#pragma unroll
        for (int r = 0; r < 4; ++r) ps[r] = rowsum16(ps[r]);
        if (col == 0) {
#pragma unroll
            for (int r = 0; r < 4; ++r) {
                int p = p0 + quad * 4 + r;
                if (p < NP) sc[p] = ps[r];
            }
        }
    }
    __syncthreads();

    // ---- softmax over 780 pairs (unnormalized exp; fold 1/sum at the end) ----
    float m = -1e30f;
    for (int p = tid; p < NP; p += 256) m = fmaxf(m, sc[p]);
#pragma unroll
    for (int off = 1; off < 64; off <<= 1) m = fmaxf(m, __shfl_xor(m, off));
    if (lane == 0) red_max[wid] = m;
    __syncthreads();
    const float M = fmaxf(fmaxf(red_max[0], red_max[1]), fmaxf(red_max[2], red_max[3]));

    float s = 0.f;
    for (int p = tid; p < NP; p += 256) {
        float e = __expf(sc[p] - M);
        sc[p] = e;
        s += e;
    }
#pragma unroll
    for (int off = 1; off < 64; off <<= 1) s += __shfl_xor(s, off);
    if (lane == 0) red_sum[wid] = s;
    __syncthreads();   // exp values visible; red_sum written

    // ---- build symmetric weight matrix G[i][j] = exp_w(pair(i,j)), diag 0 ----
    for (int p = tid; p < NP; p += 256) {
        int v = ij[p];
        float w = sc[p];
        G[(v >> 8) & 255][v & 255] = w;
        G[v & 255][(v >> 8) & 255] = w;
    }
    if (tid < NF) G[tid][tid] = 0.f;
    __syncthreads();

    // ---- afm[e] = 0.5 * sum_i x[i,e] * (G x)[i,e]  (fp32) ----
    // each wave owns 10 i-rows, lanes own 2 consecutive e; x columns in regs
    {
        const int e2 = lane * 2;
        float2 xc[NF];
#pragma unroll
        for (int j = 0; j < NF; ++j) xc[j] = *(const float2*)&xs[j][e2];

        float a0 = 0.f, a1 = 0.f;
#pragma unroll
        for (int ii = 0; ii < 10; ++ii) {
            const int i = wid * 10 + ii;
            float y0 = 0.f, y1 = 0.f;
#pragma unroll
            for (int jj = 0; jj < 10; ++jj) {
                float4 g = *(const float4*)&G[i][jj * 4];   // wave-uniform broadcast
                y0 += g.x * xc[jj * 4 + 0].x;  y1 += g.x * xc[jj * 4 + 0].y;
                y0 += g.y * xc[jj * 4 + 1].x;  y1 += g.y * xc[jj * 4 + 1].y;
                y0 += g.z * xc[jj * 4 + 2].x;  y1 += g.z * xc[jj * 4 + 2].y;
                y0 += g.w * xc[jj * 4 + 3].x;  y1 += g.w * xc[jj * 4 + 3].y;
            }
            float2 xi = *(const float2*)&xs[i][e2];         // LDS read: keeps xc[] statically indexed
            a0 += xi.x * y0;
            a1 += xi.y * y1;
        }
        *(float2*)&afmp[wid][e2] = make_float2(a0 * 0.5f, a1 * 0.5f);
    }
    __syncthreads();

    // ---- out[b] = (sum_e afm_un[e] * pw[e]) / sum_exp + p_b ----
    float vv = 0.f;
    if (tid < NE) {
        float a = afmp[0][tid] + afmp[1][tid] + afmp[2][tid] + afmp[3][tid];
        vv = a * pwg[tid];
    }
#pragma unroll
    for (int off = 1; off < 64; off <<= 1) vv += __shfl_xor(vv, off);
    if (lane == 0) red_out[wid] = vv;
    __syncthreads();
    if (tid == 0) {
        float S   = red_sum[0] + red_sum[1] + red_sum[2] + red_sum[3];
        float tot = red_out[0] + red_out[1] + red_out[2] + red_out[3];
        out[b] = tot / S + pbg[0];
    }
}

extern "C" void kernel_launch(void* const* d_in, const int* in_sizes, int n_in,
                              void* d_out, int out_size, void* d_ws, size_t ws_size,
                              hipStream_t stream) {
    const float* xg  = (const float*)d_in[0];  // x [B,F,E]
    const float* wg  = (const float*)d_in[1];  // attn_w_w [A,E]
    const float* wbg = (const float*)d_in[2];  // attn_w_b [A]
    const float* hg  = (const float*)d_in[3];  // attn_h_w [1,A]
    // d_in[4] = attn_h_b : constant shift, cancels in softmax
    const float* pwg = (const float*)d_in[5];  // attn_p_w [1,E]
    const float* pbg = (const float*)d_in[6];  // attn_p_b [1]
    const int B = in_sizes[0] / (NF * NE);

    unsigned short* wbf = (unsigned short*)d_ws;                        // 32768 B (f16 W)
    int* ijg = (int*)((char*)d_ws + NA * NE * sizeof(unsigned short));  // 3136 B

    afm_prep_kernel<<<16, 256, 0, stream>>>(wg, wbf, ijg);
    afm_fused_kernel<<<B, 256, 0, stream>>>(xg, wbf, ijg, wbg, hg, pwg, pbg, (float*)d_out);
}